// Round 8
// baseline (134.172 us; speedup 1.0000x reference)
//
#include <hip/hip_runtime.h>

// DCNv2 fused, round 8: barrier-free split-K across waves, B-frags in registers.
// B=8, Cin=Cout=128, H=W=Ho=Wo=64, kh=kw=3, stride=1, pad=1, dil=1.
//
// R5-R7 all plateau ~40us main-kernel: the per-step __syncthreads (vmcnt(0)
// drain) between staging and MFMA is structural. R8 removes it: wave w owns
// ci-slice [32w, 32w+32). In channels-last inT, a B-fragment (8 consecutive
// ci at one p) is one contiguous 16B load, so each lane builds its B-frag in
// registers from its 4 bilinear taps. K-loop: 9 steps of (8 gather dwordx4 +
// 8 A-frag loads + bilerp/convert VALU + 16 MFMA), NO barrier, NO LDS.
// Epilogue: 4 partial C's (128co x 32p each) reduced through LDS (3 barriers).
//
// grid 1024 = (ph, ho, b): b = blk&7 (XCD swizzle), ho=(blk>>3)&63, ph=blk>>9.
// 256 thr = 4 waves; __launch_bounds__(256,3): 170-VGPR cap, 3 blocks/CU.

constexpr int CIN = 128, COUT = 128, H = 64, W = 64, KK = 9;
constexpr int HW = H * W;
constexpr int RST = 33;  // reduction buffer row stride (floats, pad +1)

typedef __attribute__((ext_vector_type(8))) short short8;
typedef __attribute__((ext_vector_type(4))) float float4v;

static __device__ __forceinline__ unsigned short f32_to_bf16_rne(float f) {
  unsigned u = __float_as_uint(f);
  return (unsigned short)((u + 0x7FFFu + ((u >> 16) & 1u)) >> 16);
}
static __device__ __forceinline__ float blo(unsigned u) {
  return __uint_as_float(u << 16);
}
static __device__ __forceinline__ float bhi(unsigned u) {
  return __uint_as_float(u & 0xFFFF0000u);
}
// one dword (2 ci) of a B-frag: bilinear-combine 4 taps, round to bf16 pair
static __device__ __forceinline__ unsigned pkdw(unsigned u00, unsigned u01,
                                                unsigned u10, unsigned u11,
                                                float4 Wc) {
  const float se = Wc.x * blo(u00) + Wc.y * blo(u01) + Wc.z * blo(u10) +
                   Wc.w * blo(u11);
  const float so = Wc.x * bhi(u00) + Wc.y * bhi(u01) + Wc.z * bhi(u10) +
                   Wc.w * bhi(u11);
  return (unsigned)f32_to_bf16_rne(se) | ((unsigned)f32_to_bf16_rne(so) << 16);
}
static __device__ __forceinline__ short8 bilerp8(uint4 t00, uint4 t01,
                                                 uint4 t10, uint4 t11,
                                                 float4 Wc) {
  union { uint4 u; short8 s; } r;
  r.u = make_uint4(pkdw(t00.x, t01.x, t10.x, t11.x, Wc),
                   pkdw(t00.y, t01.y, t10.y, t11.y, Wc),
                   pkdw(t00.z, t01.z, t10.z, t11.z, Wc),
                   pkdw(t00.w, t01.w, t10.w, t11.w, Wc));
  return r.s;
}

// ---- transpose prep: input[b][ci][y][x] f32 -> inT[b][y][x][ci] bf16 ----
__global__ __launch_bounds__(256) void tprep_kernel(
    const float* __restrict__ in, unsigned short* __restrict__ inT) {
  __shared__ unsigned short lt[64 * 130];  // [x][ci], pad 130
  const int b = blockIdx.x >> 6, y = blockIdx.x & 63;
  for (int i = threadIdx.x; i < 128 * 64; i += 256) {
    const int ci = i >> 6, x = i & 63;
    lt[x * 130 + ci] = f32_to_bf16_rne(in[((b * 128 + ci) * 64 + y) * 64 + x]);
  }
  __syncthreads();
  unsigned* outp = (unsigned*)inT + (size_t)(b * 64 + y) * 64 * 64;
  for (int i = threadIdx.x; i < 64 * 64; i += 256) {
    const int x = i >> 6, c2 = (i & 63) * 2;
    outp[x * 64 + (i & 63)] =
        (unsigned)lt[x * 130 + c2] | ((unsigned)lt[x * 130 + c2 + 1] << 16);
  }
}

// ---- weight prep: w[co][ci][k] fp32 -> bf16 A-fragments ----
// wt[(k*4+ks)*8 + c16][lane][j]; value = w[co=c16*16+(lane&15)]
//                                         [ci=ks*32+(lane>>4)*8+j][k]
__global__ __launch_bounds__(256) void wprep_kernel(
    const float* __restrict__ w, unsigned short* __restrict__ wt) {
  const int t = blockIdx.x * 256 + threadIdx.x;
  if (t >= 9 * 4 * 8 * 64) return;
  const int lane = t & 63, c16 = (t >> 6) & 7, kt = t >> 9;
  const int ks = kt & 3, k = kt >> 2;
  const int co = c16 * 16 + (lane & 15);
  const int ci0 = ks * 32 + (lane >> 4) * 8;
  unsigned pk[4];
#pragma unroll
  for (int jj = 0; jj < 4; ++jj) {
    const unsigned short h0 =
        f32_to_bf16_rne(w[(co * CIN + ci0 + 2 * jj) * KK + k]);
    const unsigned short h1 =
        f32_to_bf16_rne(w[(co * CIN + ci0 + 2 * jj + 1) * KK + k]);
    pk[jj] = (unsigned)h0 | ((unsigned)h1 << 16);
  }
  *(uint4*)(wt + (size_t)t * 8) = make_uint4(pk[0], pk[1], pk[2], pk[3]);
}

__global__ __launch_bounds__(256, 3) void dcn_mfma_kernel(
    const unsigned short* __restrict__ inT, const float* __restrict__ offset,
    const float* __restrict__ mask, const unsigned short* __restrict__ wt,
    const float* __restrict__ bias, float* __restrict__ out) {
  __shared__ int2 pos_i[KK * 32];    // channels-last elem base: row0, row1
  __shared__ float4 pos_w[KK * 32];  // folded slot weights cA0,cB0,cA1,cB1
  __shared__ float red0[128 * RST];  // reduction buffers (pad-33 rows)
  __shared__ float red1[128 * RST];

  const int b = blockIdx.x & 7;  // XCD swizzle: batch b -> XCD b L2
  const int ho = (blockIdx.x >> 3) & 63;
  const int ph = blockIdx.x >> 9;
  const int tid = threadIdx.x;

  // ---- Phase A: per-(k,p) tables; taps folded onto slots (bx, bx+1) ----
  for (int idx = tid; idx < KK * 32; idx += 256) {
    const int k = idx >> 5, p = idx & 31;
    const int pg = ph * 32 + p;
    const int ky = k / 3, kx = k - 3 * ky;
    const float py = (float)(ho - 1 + ky) +
                     offset[((b * 18 + 2 * k) * 64 + ho) * 64 + pg];
    const float px = (float)(pg - 1 + kx) +
                     offset[((b * 18 + 2 * k + 1) * 64 + ho) * 64 + pg];
    const float m = mask[((b * 9 + k) * 64 + ho) * 64 + pg];
    const float y0f = floorf(py), x0f = floorf(px);
    const int y0 = (int)y0f, x0 = (int)x0f;
    const float ly = py - y0f, lx = px - x0f;
    const float hy = 1.f - ly, hx = 1.f - lx;
    const bool vy0 = (y0 >= 0) && (y0 < H);
    const bool vy1 = (y0 + 1 >= 0) && (y0 + 1 < H);
    const bool vx0 = (x0 >= 0) && (x0 < W);
    const bool vx1 = (x0 + 1 >= 0) && (x0 + 1 < W);
    const float w00 = (vy0 && vx0) ? hy * hx * m : 0.f;
    const float w01 = (vy0 && vx1) ? hy * lx * m : 0.f;
    const float w10 = (vy1 && vx0) ? ly * hx * m : 0.f;
    const float w11 = (vy1 && vx1) ? ly * lx * m : 0.f;
    const int cy0 = min(max(y0, 0), H - 1), cy1 = min(max(y0 + 1, 0), H - 1);
    const int bx = min(max(x0, 0), W - 2);
    const int s0 = min(max(x0 - bx, 0), 1);
    const int s1 = min(max(x0 + 1 - bx, 0), 1);
    // exact fold: invalid taps weigh 0; shared slots add a zero term
    const float cA0 = (s0 == 0 ? w00 : 0.f) + (s1 == 0 ? w01 : 0.f);
    const float cB0 = (s0 == 1 ? w00 : 0.f) + (s1 == 1 ? w01 : 0.f);
    const float cA1 = (s0 == 0 ? w10 : 0.f) + (s1 == 0 ? w11 : 0.f);
    const float cB1 = (s0 == 1 ? w10 : 0.f) + (s1 == 1 ? w11 : 0.f);
    pos_i[idx] = make_int2((cy0 * 64 + bx) * 128, (cy1 * 64 + bx) * 128);
    pos_w[idx] = make_float4(cA0, cB0, cA1, cB1);
  }
  __syncthreads();  // tables ready; LAST barrier before the K-loop

  const int wave = tid >> 6;   // = ks: this wave's 32-ci slice
  const int lane = tid & 63;
  const int quad = lane >> 4, l15 = lane & 15;
  const int ciofs = wave * 32 + quad * 8;  // elem offset within a position

  float4v acc[8][2];  // partial C over this wave's ci-slice: [sub=co16][ns]
#pragma unroll
  for (int s = 0; s < 8; ++s)
#pragma unroll
    for (int n = 0; n < 2; ++n) acc[s][n] = (float4v)(0.f);

  const unsigned short* inb = inT + (size_t)b * HW * 128;

  // ---- barrier-free K-loop: 9 steps, each K=32 (one MFMA-K per wave) ----
  for (int k = 0; k < KK; ++k) {
    const int2 P0 = pos_i[k * 32 + l15];
    const float4 W0 = pos_w[k * 32 + l15];
    const int2 P1 = pos_i[k * 32 + 16 + l15];
    const float4 W1 = pos_w[k * 32 + 16 + l15];
    // 8 gathers (coalesced dwordx4; each lane's 16B within one 64B line)
    const unsigned short* r00 = inb + P0.x + ciofs;
    const unsigned short* r01 = inb + P0.y + ciofs;
    const unsigned short* r10 = inb + P1.x + ciofs;
    const unsigned short* r11 = inb + P1.y + ciofs;
    const uint4 t0a = *(const uint4*)r00;
    const uint4 t0b = *(const uint4*)(r00 + 128);
    const uint4 t0c = *(const uint4*)r01;
    const uint4 t0d = *(const uint4*)(r01 + 128);
    const uint4 t1a = *(const uint4*)r10;
    const uint4 t1b = *(const uint4*)(r10 + 128);
    const uint4 t1c = *(const uint4*)r11;
    const uint4 t1d = *(const uint4*)(r11 + 128);
    // 8 A-frags (same bytes for all blocks on a CU -> L1 hits)
    const unsigned short* wk =
        wt + ((size_t)(k * 4 + wave) * 8) * 512 + (size_t)lane * 8;
    short8 A[8];
#pragma unroll
    for (int sub = 0; sub < 8; ++sub)
      A[sub] = *(const short8*)(wk + (size_t)sub * 512);
    // build both B-frags in registers
    const short8 B0 = bilerp8(t0a, t0b, t0c, t0d, W0);
    const short8 B1 = bilerp8(t1a, t1b, t1c, t1d, W1);
    // 16 MFMA
#pragma unroll
    for (int sub = 0; sub < 8; ++sub) {
      acc[sub][0] =
          __builtin_amdgcn_mfma_f32_16x16x32_bf16(A[sub], B0, acc[sub][0], 0, 0, 0);
      acc[sub][1] =
          __builtin_amdgcn_mfma_f32_16x16x32_bf16(A[sub], B1, acc[sub][1], 0, 0, 0);
    }
  }

  // ---- epilogue: reduce 4 wave-partials via LDS, add bias, store ----
  // C/D layout: col(N=p)=l15, row(M within sub)=quad*4+r.
  if (wave == 2) {
#pragma unroll
    for (int sub = 0; sub < 8; ++sub)
#pragma unroll
      for (int ns = 0; ns < 2; ++ns)
#pragma unroll
        for (int r = 0; r < 4; ++r)
          red0[(sub * 16 + quad * 4 + r) * RST + ns * 16 + l15] =
              acc[sub][ns][r];
  } else if (wave == 3) {
#pragma unroll
    for (int sub = 0; sub < 8; ++sub)
#pragma unroll
      for (int ns = 0; ns < 2; ++ns)
#pragma unroll
        for (int r = 0; r < 4; ++r)
          red1[(sub * 16 + quad * 4 + r) * RST + ns * 16 + l15] =
              acc[sub][ns][r];
  }
  __syncthreads();
  if (wave == 0) {
#pragma unroll
    for (int sub = 0; sub < 8; ++sub)
#pragma unroll
      for (int ns = 0; ns < 2; ++ns)
#pragma unroll
        for (int r = 0; r < 4; ++r)
          acc[sub][ns][r] +=
              red0[(sub * 16 + quad * 4 + r) * RST + ns * 16 + l15];
  } else if (wave == 1) {
#pragma unroll
    for (int sub = 0; sub < 8; ++sub)
#pragma unroll
      for (int ns = 0; ns < 2; ++ns)
#pragma unroll
        for (int r = 0; r < 4; ++r)
          acc[sub][ns][r] +=
              red1[(sub * 16 + quad * 4 + r) * RST + ns * 16 + l15];
  }
  __syncthreads();
  if (wave == 1) {  // publish sum(1+3)
#pragma unroll
    for (int sub = 0; sub < 8; ++sub)
#pragma unroll
      for (int ns = 0; ns < 2; ++ns)
#pragma unroll
        for (int r = 0; r < 4; ++r)
          red0[(sub * 16 + quad * 4 + r) * RST + ns * 16 + l15] =
              acc[sub][ns][r];
  }
  __syncthreads();
  if (wave == 0) {  // final = sum(0+2) + sum(1+3) + bias -> out
#pragma unroll
    for (int sub = 0; sub < 8; ++sub) {
#pragma unroll
      for (int r = 0; r < 4; ++r) {
        const int co = sub * 16 + quad * 4 + r;
        const float bb = bias[co];
        float* op = out + ((size_t)(b * COUT + co) * H + ho) * W + ph * 32;
#pragma unroll
        for (int ns = 0; ns < 2; ++ns)
          op[ns * 16 + l15] =
              acc[sub][ns][r] + red0[co * RST + ns * 16 + l15] + bb;
      }
    }
  }
}

// ---- fallback (ws too small): round-1 fp32 kernel ----
__global__ __launch_bounds__(256) void dcn_fp32_kernel(
    const float* __restrict__ input, const float* __restrict__ offset,
    const float* __restrict__ mask, const float* __restrict__ weight,
    const float* __restrict__ bias, float* __restrict__ out) {
  __shared__ short4 pos_o[KK * 64];
  __shared__ float4 pos_w[KK * 64];
  __shared__ float s_tile[64 * 64];
  __shared__ float w_tile[64 * 128];
  const int b = blockIdx.x >> 6;
  const int ho = blockIdx.x & 63;
  const int tid = threadIdx.x;
  for (int idx = tid; idx < KK * 64; idx += 256) {
    const int k = idx >> 6, pp = idx & 63;
    const int ky = k / 3, kx = k - 3 * ky;
    const float py = (float)(ho - 1 + ky) +
                     offset[((b * 18 + 2 * k) * 64 + ho) * 64 + pp];
    const float px = (float)(pp - 1 + kx) +
                     offset[((b * 18 + 2 * k + 1) * 64 + ho) * 64 + pp];
    const float m = mask[((b * 9 + k) * 64 + ho) * 64 + pp];
    const float y0f = floorf(py), x0f = floorf(px);
    const int y0 = (int)y0f, x0 = (int)x0f;
    const float ly = py - y0f, lx = px - x0f;
    const float hy = 1.f - ly, hx = 1.f - lx;
    const bool vy0 = (y0 >= 0) && (y0 < H), vy1 = (y0 + 1 >= 0) && (y0 + 1 < H);
    const bool vx0 = (x0 >= 0) && (x0 < W), vx1 = (x0 + 1 >= 0) && (x0 + 1 < W);
    const int cy0 = min(max(y0, 0), H - 1), cy1 = min(max(y0 + 1, 0), H - 1);
    const int cx0 = min(max(x0, 0), W - 1), cx1 = min(max(x0 + 1, 0), W - 1);
    pos_o[idx] = make_short4((short)(cy0 * W + cx0), (short)(cy0 * W + cx1),
                             (short)(cy1 * W + cx0), (short)(cy1 * W + cx1));
    pos_w[idx] = make_float4((vy0 && vx0) ? hy * hx * m : 0.f,
                             (vy0 && vx1) ? hy * lx * m : 0.f,
                             (vy1 && vx0) ? ly * hx * m : 0.f,
                             (vy1 && vx1) ? ly * lx * m : 0.f);
  }
  const int cog = tid >> 4, pg = tid & 15;
  float acc[8][4];
#pragma unroll
  for (int j = 0; j < 8; ++j)
#pragma unroll
    for (int q = 0; q < 4; ++q) acc[j][q] = 0.f;
  const float* inp_b = input + (size_t)b * CIN * HW;
  for (int k = 0; k < KK; ++k) {
    for (int cc = 0; cc < 2; ++cc) {
      __syncthreads();
      for (int i = tid; i < 64 * 64; i += 256) {
        const int cil = i >> 6, pp = i & 63;
        const float* plane = inp_b + (size_t)(cc * 64 + cil) * HW;
        const short4 o = pos_o[k * 64 + pp];
        const float4 w = pos_w[k * 64 + pp];
        s_tile[i] = w.x * plane[(int)o.x] + w.y * plane[(int)o.y] +
                    w.z * plane[(int)o.z] + w.w * plane[(int)o.w];
      }
      for (int i = tid; i < 64 * 128; i += 256) {
        const int cil = i & 63, co = i >> 6;
        w_tile[cil * 128 + co] = weight[(co * CIN + cc * 64 + cil) * KK + k];
      }
      __syncthreads();
#pragma unroll 8
      for (int cil = 0; cil < 64; ++cil) {
        const float4 sv = *(const float4*)&s_tile[cil * 64 + (pg << 2)];
        const float4 wa = *(const float4*)&w_tile[cil * 128 + (cog << 3)];
        const float4 wb = *(const float4*)&w_tile[cil * 128 + (cog << 3) + 4];
        const float s4[4] = {sv.x, sv.y, sv.z, sv.w};
        const float w8[8] = {wa.x, wa.y, wa.z, wa.w, wb.x, wb.y, wb.z, wb.w};
#pragma unroll
        for (int j = 0; j < 8; ++j)
#pragma unroll
          for (int q = 0; q < 4; ++q) acc[j][q] = fmaf(w8[j], s4[q], acc[j][q]);
      }
    }
  }
  float* outp = out + (size_t)b * COUT * HW + ho * W;
#pragma unroll
  for (int j = 0; j < 8; ++j) {
    const int co = (cog << 3) + j;
    const float bb = bias[co];
    *(float4*)&outp[co * HW + (pg << 2)] =
        make_float4(acc[j][0] + bb, acc[j][1] + bb, acc[j][2] + bb,
                    acc[j][3] + bb);
  }
}

extern "C" void kernel_launch(void* const* d_in, const int* in_sizes, int n_in,
                              void* d_out, int out_size, void* d_ws,
                              size_t ws_size, hipStream_t stream) {
  const float* input = (const float*)d_in[0];
  const float* offset = (const float*)d_in[1];
  const float* mask = (const float*)d_in[2];
  const float* weight = (const float*)d_in[3];
  const float* bias = (const float*)d_in[4];
  float* out = (float*)d_out;

  const size_t wt_bytes = (size_t)9 * 4 * 8 * 64 * 8 * 2;  // 294912
  const size_t inT_bytes = (size_t)8 * HW * 128 * 2;       // 8388608
  if (ws_size >= wt_bytes + inT_bytes) {
    unsigned short* wt = (unsigned short*)d_ws;
    unsigned short* inT = (unsigned short*)((char*)d_ws + wt_bytes);
    hipLaunchKernelGGL(wprep_kernel, dim3(72), dim3(256), 0, stream, weight, wt);
    hipLaunchKernelGGL(tprep_kernel, dim3(512), dim3(256), 0, stream, input, inT);
    hipLaunchKernelGGL(dcn_mfma_kernel, dim3(1024), dim3(256), 0, stream, inT,
                       offset, mask, wt, bias, out);
  } else {
    hipLaunchKernelGGL(dcn_fp32_kernel, dim3(512), dim3(256), 0, stream, input,
                       offset, mask, weight, bias, out);
  }
}

// Round 9
// 104.890 us; speedup vs baseline: 1.2792x; 1.2792x over previous
//
#include <hip/hip_runtime.h>

// DCNv2 fused, round 9: R5 structure, full-row blocks, halved A-traffic.
// B=8, Cin=Cout=128, H=W=Ho=Wo=64, kh=kw=3, stride=1, pad=1, dil=1.
//
// R8 post-mortem: wall = L1 segment throughput (gather segments + A-frag
// segments). R9 = R5's proven shape (512 thr, staged s-tile, 1 barrier/step)
// with: (1) 64 p per block (grid 512, no ph-split) -> A global traffic and
// Phase-A work HALVED (each 16-co A-slice loaded once per block-step);
// (2) __launch_bounds__(512,4) -> 128-VGPR cap so the 32-VGPR gather
// prefetch stays resident (R5's (512,8)=64-cap sank it); (3) xor-swizzled
// s-tile (R5's SROW=136 B-reads were 8-way bank-conflicted).
//
// grid 512 = (ho, b): b = blk&7 (XCD swizzle: batch b -> XCD b, input slice
// L2-resident), ho = blk>>3. Block tile 128co x 64p; 8 waves, wave w:
// co 16w..16w+15, 4 ns x 4 ks = 16 MFMA 16x16x32_bf16 per k-step.
// Per step: convert+stage s_t[buf] (waits gathers k) -> barrier -> A(k) loads
// (issued BEFORE gathers(k+1): FIFO vmcnt wait for MFMA leaves prefetch in
// flight) -> issue gathers(k+1) -> 16 ds_read_b128 + 16 MFMA.

constexpr int CIN = 128, COUT = 128, H = 64, W = 64, KK = 9;
constexpr int HW = H * W;

typedef __attribute__((ext_vector_type(8))) short short8;
typedef __attribute__((ext_vector_type(4))) float float4v;

static __device__ __forceinline__ unsigned short f32_to_bf16_rne(float f) {
  unsigned u = __float_as_uint(f);
  return (unsigned short)((u + 0x7FFFu + ((u >> 16) & 1u)) >> 16);
}
static __device__ __forceinline__ float blo(unsigned u) {
  return __uint_as_float(u << 16);
}
static __device__ __forceinline__ float bhi(unsigned u) {
  return __uint_as_float(u & 0xFFFF0000u);
}

// ---- transpose prep: input[b][ci][y][x] f32 -> inT[b][y][x][ci] bf16 ----
__global__ __launch_bounds__(256) void tprep_kernel(
    const float* __restrict__ in, unsigned short* __restrict__ inT) {
  __shared__ unsigned short lt[64 * 130];  // [x][ci], pad 130
  const int b = blockIdx.x >> 6, y = blockIdx.x & 63;
  for (int i = threadIdx.x; i < 128 * 64; i += 256) {
    const int ci = i >> 6, x = i & 63;
    lt[x * 130 + ci] = f32_to_bf16_rne(in[((b * 128 + ci) * 64 + y) * 64 + x]);
  }
  __syncthreads();
  unsigned* outp = (unsigned*)inT + (size_t)(b * 64 + y) * 64 * 64;
  for (int i = threadIdx.x; i < 64 * 64; i += 256) {
    const int x = i >> 6, c2 = (i & 63) * 2;
    outp[x * 64 + (i & 63)] =
        (unsigned)lt[x * 130 + c2] | ((unsigned)lt[x * 130 + c2 + 1] << 16);
  }
}

// ---- weight prep: w[co][ci][k] fp32 -> bf16 A-fragments ----
// wt[(k*4+ks)*8 + c16][lane][j]; value = w[co=c16*16+(lane&15)]
//                                         [ci=ks*32+(lane>>4)*8+j][k]
__global__ __launch_bounds__(256) void wprep_kernel(
    const float* __restrict__ w, unsigned short* __restrict__ wt) {
  const int t = blockIdx.x * 256 + threadIdx.x;
  if (t >= 9 * 4 * 8 * 64) return;
  const int lane = t & 63, c16 = (t >> 6) & 7, kt = t >> 9;
  const int ks = kt & 3, k = kt >> 2;
  const int co = c16 * 16 + (lane & 15);
  const int ci0 = ks * 32 + (lane >> 4) * 8;
  unsigned pk[4];
#pragma unroll
  for (int jj = 0; jj < 4; ++jj) {
    const unsigned short h0 =
        f32_to_bf16_rne(w[(co * CIN + ci0 + 2 * jj) * KK + k]);
    const unsigned short h1 =
        f32_to_bf16_rne(w[(co * CIN + ci0 + 2 * jj + 1) * KK + k]);
    pk[jj] = (unsigned)h0 | ((unsigned)h1 << 16);
  }
  *(uint4*)(wt + (size_t)t * 8) = make_uint4(pk[0], pk[1], pk[2], pk[3]);
}

__global__ __launch_bounds__(512, 4) void dcn_mfma_kernel(
    const unsigned short* __restrict__ inT, const float* __restrict__ offset,
    const float* __restrict__ mask, const unsigned short* __restrict__ wt,
    const float* __restrict__ bias, float* __restrict__ out) {
  __shared__ int2 pos_i[KK * 64];    // channels-last elem base: row0, row1
  __shared__ float4 pos_w[KK * 64];  // folded slot weights cA0,cB0,cA1,cB1
  __shared__ unsigned short s_t[2][64 * 128];  // dbuf [p][ci], xor-swizzled

  const int b = blockIdx.x & 7;  // XCD swizzle: batch b -> XCD b (L2 locality)
  const int ho = blockIdx.x >> 3;
  const int tid = threadIdx.x;

  // ---- Phase A: per-(k,p) tables; taps folded onto slots (bx, bx+1) ----
  for (int idx = tid; idx < KK * 64; idx += 512) {
    const int k = idx >> 6, p = idx & 63;
    const int ky = k / 3, kx = k - 3 * ky;
    const float py = (float)(ho - 1 + ky) +
                     offset[((b * 18 + 2 * k) * 64 + ho) * 64 + p];
    const float px = (float)(p - 1 + kx) +
                     offset[((b * 18 + 2 * k + 1) * 64 + ho) * 64 + p];
    const float m = mask[((b * 9 + k) * 64 + ho) * 64 + p];
    const float y0f = floorf(py), x0f = floorf(px);
    const int y0 = (int)y0f, x0 = (int)x0f;
    const float ly = py - y0f, lx = px - x0f;
    const float hy = 1.f - ly, hx = 1.f - lx;
    const bool vy0 = (y0 >= 0) && (y0 < H);
    const bool vy1 = (y0 + 1 >= 0) && (y0 + 1 < H);
    const bool vx0 = (x0 >= 0) && (x0 < W);
    const bool vx1 = (x0 + 1 >= 0) && (x0 + 1 < W);
    const float w00 = (vy0 && vx0) ? hy * hx * m : 0.f;
    const float w01 = (vy0 && vx1) ? hy * lx * m : 0.f;
    const float w10 = (vy1 && vx0) ? ly * hx * m : 0.f;
    const float w11 = (vy1 && vx1) ? ly * lx * m : 0.f;
    const int cy0 = min(max(y0, 0), H - 1), cy1 = min(max(y0 + 1, 0), H - 1);
    const int bx = min(max(x0, 0), W - 2);
    const int s0 = min(max(x0 - bx, 0), 1);
    const int s1 = min(max(x0 + 1 - bx, 0), 1);
    // exact fold: invalid taps weigh 0; shared slots add a zero term
    const float cA0 = (s0 == 0 ? w00 : 0.f) + (s1 == 0 ? w01 : 0.f);
    const float cB0 = (s0 == 1 ? w00 : 0.f) + (s1 == 1 ? w01 : 0.f);
    const float cA1 = (s0 == 0 ? w10 : 0.f) + (s1 == 0 ? w11 : 0.f);
    const float cB1 = (s0 == 1 ? w10 : 0.f) + (s1 == 1 ? w11 : 0.f);
    pos_i[idx] = make_int2((cy0 * 64 + bx) * 128, (cy1 * 64 + bx) * 128);
    pos_w[idx] = make_float4(cA0, cB0, cA1, cB1);
  }
  __syncthreads();

  const int wave = tid >> 6;  // 0..7 -> co block of 16 (unique: no A redundancy)
  const int lane = tid & 63;
  const int quad = lane >> 4, l15 = lane & 15;
  const int p_loc = tid >> 3;  // 0..63: staged p row
  const int cg8 = tid & 7;     // ci chunk of 16 (two 16B granules)

  float4v acc[4];  // [ns = p 16-block]
#pragma unroll
  for (int n = 0; n < 4; ++n) acc[n] = (float4v)(0.f);

  const unsigned short* inb = inT + (size_t)b * HW * 128;

  // prologue: gathers for k=0 (8 dwordx4 = 32 VGPRs in flight)
  int2 P = pos_i[p_loc];
  float4 Wc = pos_w[p_loc];
  uint4 ga0, ga1, gb0, gb1, gc0, gc1, gd0, gd1;
  {
    const unsigned short* a0 = inb + P.x + cg8 * 16;
    const unsigned short* a1 = inb + P.y + cg8 * 16;
    ga0 = *(const uint4*)a0;
    ga1 = *(const uint4*)(a0 + 8);
    gb0 = *(const uint4*)(a0 + 128);
    gb1 = *(const uint4*)(a0 + 136);
    gc0 = *(const uint4*)a1;
    gc1 = *(const uint4*)(a1 + 8);
    gd0 = *(const uint4*)(a1 + 128);
    gd1 = *(const uint4*)(a1 + 136);
  }

  for (int k = 0; k < KK; ++k) {
    const int buf = k & 1;
    // ---- convert + stage: s[ci] = cA0*v00 + cB0*v01 + cA1*v10 + cB1*v11 ----
    {
      const uint4 A4[2] = {ga0, ga1}, B4[2] = {gb0, gb1};
      const uint4 C4[2] = {gc0, gc1}, D4[2] = {gd0, gd1};
#pragma unroll
      for (int h = 0; h < 2; ++h) {
        const unsigned u00[4] = {A4[h].x, A4[h].y, A4[h].z, A4[h].w};
        const unsigned u01[4] = {B4[h].x, B4[h].y, B4[h].z, B4[h].w};
        const unsigned u10[4] = {C4[h].x, C4[h].y, C4[h].z, C4[h].w};
        const unsigned u11[4] = {D4[h].x, D4[h].y, D4[h].z, D4[h].w};
        unsigned pk[4];
#pragma unroll
        for (int j = 0; j < 4; ++j) {
          const float se = Wc.x * blo(u00[j]) + Wc.y * blo(u01[j]) +
                           Wc.z * blo(u10[j]) + Wc.w * blo(u11[j]);
          const float so = Wc.x * bhi(u00[j]) + Wc.y * bhi(u01[j]) +
                           Wc.z * bhi(u10[j]) + Wc.w * bhi(u11[j]);
          pk[j] = (unsigned)f32_to_bf16_rne(se) |
                  ((unsigned)f32_to_bf16_rne(so) << 16);
        }
        const int gi = cg8 * 2 + h;        // logical 16B granule
        const int pgr = gi ^ (p_loc & 7);  // xor swizzle
        *(uint4*)&s_t[buf][p_loc * 128 + pgr * 8] =
            make_uint4(pk[0], pk[1], pk[2], pk[3]);
      }
    }
    __syncthreads();  // nothing outstanding: free drain

    // ---- A(k) for this wave's unique 16-co slice (issued BEFORE prefetch:
    //      FIFO vmcnt wait for MFMA leaves the newer gathers in flight) ----
    short8 A0, A1, A2, A3;
    {
      const unsigned short* wk =
          wt + ((size_t)(k * 4) * 8 + wave) * 512 + (size_t)lane * 8;
      A0 = *(const short8*)(wk);
      A1 = *(const short8*)(wk + 8 * 512);
      A2 = *(const short8*)(wk + 16 * 512);
      A3 = *(const short8*)(wk + 24 * 512);
    }

    // ---- prefetch next k's gathers (hidden under ds_read + MFMA) ----
    if (k < KK - 1) {
      P = pos_i[(k + 1) * 64 + p_loc];
      Wc = pos_w[(k + 1) * 64 + p_loc];
      const unsigned short* a0 = inb + P.x + cg8 * 16;
      const unsigned short* a1 = inb + P.y + cg8 * 16;
      ga0 = *(const uint4*)a0;
      ga1 = *(const uint4*)(a0 + 8);
      gb0 = *(const uint4*)(a0 + 128);
      gb1 = *(const uint4*)(a0 + 136);
      gc0 = *(const uint4*)a1;
      gc1 = *(const uint4*)(a1 + 8);
      gd0 = *(const uint4*)(a1 + 128);
      gd1 = *(const uint4*)(a1 + 136);
    }

    // ---- B ds_reads (xor-swizzled) + 16 MFMA ----
#pragma unroll
    for (int ks = 0; ks < 4; ++ks) {
      const short8 Ak = (ks == 0) ? A0 : (ks == 1) ? A1 : (ks == 2) ? A2 : A3;
      const int gi = ks * 4 + quad;
#pragma unroll
      for (int ns = 0; ns < 4; ++ns) {
        const int row = ns * 16 + l15;
        const short8 Bn =
            *(const short8*)&s_t[buf][row * 128 + (gi ^ (row & 7)) * 8];
        acc[ns] = __builtin_amdgcn_mfma_f32_16x16x32_bf16(Ak, Bn, acc[ns], 0, 0, 0);
      }
    }
  }

  // ---- epilogue: C/D layout col(N=p)=lane&15, row(M=co)=quad*4+reg ----
#pragma unroll
  for (int r = 0; r < 4; ++r) {
    const int co = wave * 16 + quad * 4 + r;
    const float bb = bias[co];
    float* op = out + ((size_t)(b * COUT + co) * H + ho) * W;
#pragma unroll
    for (int ns = 0; ns < 4; ++ns) op[ns * 16 + l15] = acc[ns][r] + bb;
  }
}

// ---- fallback (ws too small): round-1 fp32 kernel ----
__global__ __launch_bounds__(256) void dcn_fp32_kernel(
    const float* __restrict__ input, const float* __restrict__ offset,
    const float* __restrict__ mask, const float* __restrict__ weight,
    const float* __restrict__ bias, float* __restrict__ out) {
  __shared__ short4 pos_o[KK * 64];
  __shared__ float4 pos_w[KK * 64];
  __shared__ float s_tile[64 * 64];
  __shared__ float w_tile[64 * 128];
  const int b = blockIdx.x >> 6;
  const int ho = blockIdx.x & 63;
  const int tid = threadIdx.x;
  for (int idx = tid; idx < KK * 64; idx += 256) {
    const int k = idx >> 6, pp = idx & 63;
    const int ky = k / 3, kx = k - 3 * ky;
    const float py = (float)(ho - 1 + ky) +
                     offset[((b * 18 + 2 * k) * 64 + ho) * 64 + pp];
    const float px = (float)(pp - 1 + kx) +
                     offset[((b * 18 + 2 * k + 1) * 64 + ho) * 64 + pp];
    const float m = mask[((b * 9 + k) * 64 + ho) * 64 + pp];
    const float y0f = floorf(py), x0f = floorf(px);
    const int y0 = (int)y0f, x0 = (int)x0f;
    const float ly = py - y0f, lx = px - x0f;
    const float hy = 1.f - ly, hx = 1.f - lx;
    const bool vy0 = (y0 >= 0) && (y0 < H), vy1 = (y0 + 1 >= 0) && (y0 + 1 < H);
    const bool vx0 = (x0 >= 0) && (x0 < W), vx1 = (x0 + 1 >= 0) && (x0 + 1 < W);
    const int cy0 = min(max(y0, 0), H - 1), cy1 = min(max(y0 + 1, 0), H - 1);
    const int cx0 = min(max(x0, 0), W - 1), cx1 = min(max(x0 + 1, 0), W - 1);
    pos_o[idx] = make_short4((short)(cy0 * W + cx0), (short)(cy0 * W + cx1),
                             (short)(cy1 * W + cx0), (short)(cy1 * W + cx1));
    pos_w[idx] = make_float4((vy0 && vx0) ? hy * hx * m : 0.f,
                             (vy0 && vx1) ? hy * lx * m : 0.f,
                             (vy1 && vx0) ? ly * hx * m : 0.f,
                             (vy1 && vx1) ? ly * lx * m : 0.f);
  }
  const int cog = tid >> 4, pg = tid & 15;
  float acc[8][4];
#pragma unroll
  for (int j = 0; j < 8; ++j)
#pragma unroll
    for (int q = 0; q < 4; ++q) acc[j][q] = 0.f;
  const float* inp_b = input + (size_t)b * CIN * HW;
  for (int k = 0; k < KK; ++k) {
    for (int cc = 0; cc < 2; ++cc) {
      __syncthreads();
      for (int i = tid; i < 64 * 64; i += 256) {
        const int cil = i >> 6, pp = i & 63;
        const float* plane = inp_b + (size_t)(cc * 64 + cil) * HW;
        const short4 o = pos_o[k * 64 + pp];
        const float4 w = pos_w[k * 64 + pp];
        s_tile[i] = w.x * plane[(int)o.x] + w.y * plane[(int)o.y] +
                    w.z * plane[(int)o.z] + w.w * plane[(int)o.w];
      }
      for (int i = tid; i < 64 * 128; i += 256) {
        const int cil = i & 63, co = i >> 6;
        w_tile[cil * 128 + co] = weight[(co * CIN + cc * 64 + cil) * KK + k];
      }
      __syncthreads();
#pragma unroll 8
      for (int cil = 0; cil < 64; ++cil) {
        const float4 sv = *(const float4*)&s_tile[cil * 64 + (pg << 2)];
        const float4 wa = *(const float4*)&w_tile[cil * 128 + (cog << 3)];
        const float4 wb = *(const float4*)&w_tile[cil * 128 + (cog << 3) + 4];
        const float s4[4] = {sv.x, sv.y, sv.z, sv.w};
        const float w8[8] = {wa.x, wa.y, wa.z, wa.w, wb.x, wb.y, wb.z, wb.w};
#pragma unroll
        for (int j = 0; j < 8; ++j)
#pragma unroll
          for (int q = 0; q < 4; ++q) acc[j][q] = fmaf(w8[j], s4[q], acc[j][q]);
      }
    }
  }
  float* outp = out + (size_t)b * COUT * HW + ho * W;
#pragma unroll
  for (int j = 0; j < 8; ++j) {
    const int co = (cog << 3) + j;
    const float bb = bias[co];
    *(float4*)&outp[co * HW + (pg << 2)] =
        make_float4(acc[j][0] + bb, acc[j][1] + bb, acc[j][2] + bb,
                    acc[j][3] + bb);
  }
}

extern "C" void kernel_launch(void* const* d_in, const int* in_sizes, int n_in,
                              void* d_out, int out_size, void* d_ws,
                              size_t ws_size, hipStream_t stream) {
  const float* input = (const float*)d_in[0];
  const float* offset = (const float*)d_in[1];
  const float* mask = (const float*)d_in[2];
  const float* weight = (const float*)d_in[3];
  const float* bias = (const float*)d_in[4];
  float* out = (float*)d_out;

  const size_t wt_bytes = (size_t)9 * 4 * 8 * 64 * 8 * 2;  // 294912
  const size_t inT_bytes = (size_t)8 * HW * 128 * 2;       // 8388608
  if (ws_size >= wt_bytes + inT_bytes) {
    unsigned short* wt = (unsigned short*)d_ws;
    unsigned short* inT = (unsigned short*)((char*)d_ws + wt_bytes);
    hipLaunchKernelGGL(wprep_kernel, dim3(72), dim3(256), 0, stream, weight, wt);
    hipLaunchKernelGGL(tprep_kernel, dim3(512), dim3(256), 0, stream, input, inT);
    hipLaunchKernelGGL(dcn_mfma_kernel, dim3(512), dim3(512), 0, stream, inT,
                       offset, mask, wt, bias, out);
  } else {
    hipLaunchKernelGGL(dcn_fp32_kernel, dim3(512), dim3(256), 0, stream, input,
                       offset, mask, weight, bias, out);
  }
}